// Round 2
// baseline (2429.851 us; speedup 1.0000x reference)
//
#include <hip/hip_runtime.h>
#include <hip/hip_bf16.h>
#include <math.h>

#define N_ROWS 2000000
#define C 20
#define K 9
#define EPS 1e-5f

#define GRID_RED 2048
#define BLK 256

// ---------- helpers ----------

__device__ inline float wave_sum(float v) {
    v += __shfl_xor(v, 1);
    v += __shfl_xor(v, 2);
    v += __shfl_xor(v, 4);
    v += __shfl_xor(v, 8);
    v += __shfl_xor(v, 16);
    v += __shfl_xor(v, 32);
    return v;
}

// Reduce 40 per-thread values across the block, write one partial row per block.
__device__ inline void block_reduce_partials(float* vals, float* __restrict__ partials) {
    __shared__ float sred[BLK / 64][2 * C];
    const int lane = threadIdx.x & 63;
    const int wid = threadIdx.x >> 6;
#pragma unroll
    for (int i = 0; i < 2 * C; i++) vals[i] = wave_sum(vals[i]);
    if (lane == 0) {
#pragma unroll
        for (int i = 0; i < 2 * C; i++) sred[wid][i] = vals[i];
    }
    __syncthreads();
    if (threadIdx.x < 2 * C) {
        float s = 0.f;
#pragma unroll
        for (int w = 0; w < BLK / 64; w++) s += sred[w][threadIdx.x];
        partials[(size_t)blockIdx.x * (2 * C) + threadIdx.x] = s;
    }
}

__device__ inline void load_row20(const float* __restrict__ p, float* v) {
    const float4* q = (const float4*)p;
#pragma unroll
    for (int i = 0; i < 5; i++) {
        float4 t = q[i];
        v[4 * i + 0] = t.x; v[4 * i + 1] = t.y; v[4 * i + 2] = t.z; v[4 * i + 3] = t.w;
    }
}

__device__ inline void store_row20(float* __restrict__ p, const float* v) {
    float4* q = (float4*)p;
#pragma unroll
    for (int i = 0; i < 5; i++) {
        float4 t;
        t.x = v[4 * i + 0]; t.y = v[4 * i + 1]; t.z = v[4 * i + 2]; t.w = v[4 * i + 3];
        q[i] = t;
    }
}

// ---------- kernel A: y1 = feature @ W1 + b1, accumulate BN1 stats ----------

__global__ __launch_bounds__(BLK) void kA(const float* __restrict__ feat,
                                          const float* __restrict__ W1,
                                          const float* __restrict__ b1,
                                          float* __restrict__ y1,
                                          float* __restrict__ partials) {
    float sums[2 * C];
#pragma unroll
    for (int i = 0; i < 2 * C; i++) sums[i] = 0.f;

    for (int r = blockIdx.x * BLK + threadIdx.x; r < N_ROWS; r += GRID_RED * BLK) {
        float f[C];
        load_row20(feat + (size_t)r * C, f);
        float y[C];
#pragma unroll
        for (int c = 0; c < C; c++) y[c] = b1[c];
#pragma unroll
        for (int i = 0; i < C; i++) {
            float fi = f[i];
#pragma unroll
            for (int c = 0; c < C; c++) y[c] = fmaf(fi, W1[i * C + c], y[c]);
        }
        store_row20(y1 + (size_t)r * C, y);
#pragma unroll
        for (int c = 0; c < C; c++) {
            sums[c] += y[c];
            sums[C + c] = fmaf(y[c], y[c], sums[C + c]);
        }
    }
    block_reduce_partials(sums, partials);
}

// ---------- finalize: partials -> scale/shift ----------

__global__ __launch_bounds__(640) void kFin(const float* __restrict__ partials,
                                            const float* __restrict__ g,
                                            const float* __restrict__ be,
                                            float* __restrict__ ss) {
    const int c = threadIdx.x >> 4;   // 40 channels x 16 threads
    const int r = threadIdx.x & 15;
    __shared__ float tot[2 * C];
    {
        float s = 0.f;
        for (int b = r; b < GRID_RED; b += 16) s += partials[(size_t)b * (2 * C) + c];
        s += __shfl_xor(s, 1);
        s += __shfl_xor(s, 2);
        s += __shfl_xor(s, 4);
        s += __shfl_xor(s, 8);
        if (r == 0) tot[c] = s;
    }
    __syncthreads();
    if (threadIdx.x < C) {
        const int cc = threadIdx.x;
        const float invN = 1.0f / (float)N_ROWS;
        float mean = tot[cc] * invN;
        float var = tot[C + cc] * invN - mean * mean;
        float scale = g[cc] * rsqrtf(var + EPS);
        ss[cc] = scale;
        ss[C + cc] = be[cc] - mean * scale;
    }
}

// ---------- kernel C: attention pass 1 (online softmax), out + weights ----------

__global__ __launch_bounds__(BLK) void kC(const float* __restrict__ y1,
                                          const int* __restrict__ index,
                                          const float* __restrict__ ss1,
                                          float* __restrict__ out,
                                          float* __restrict__ wbuf) {
    const int n = blockIdx.x * BLK + threadIdx.x;
    if (n >= N_ROWS) return;

    float sc[C], sh[C];
#pragma unroll
    for (int c = 0; c < C; c++) { sc[c] = ss1[c]; sh[c] = ss1[C + c]; }

    float x[C];
    {
        float t[C];
        load_row20(y1 + (size_t)n * C, t);
#pragma unroll
        for (int c = 0; c < C; c++) x[c] = fmaf(t[c], sc[c], sh[c]);
    }

    int idx[K];
#pragma unroll
    for (int k = 0; k < K; k++) idx[k] = index[(size_t)n * K + k];

    float m = -INFINITY, l = 0.f;
    float acc[C];
    float s[K];
#pragma unroll
    for (int c = 0; c < C; c++) acc[c] = 0.f;

#pragma unroll
    for (int k = 0; k < K; k++) {
        float gch[C];
        {
            float t[C];
            load_row20(y1 + (size_t)idx[k] * C, t);
#pragma unroll
            for (int c = 0; c < C; c++) gch[c] = fmaf(t[c], sc[c], sh[c]);
        }
        float d0 = 0.f, d1 = 0.f;
#pragma unroll
        for (int c = 0; c < C; c += 2) {
            d0 = fmaf(x[c], gch[c], d0);
            d1 = fmaf(x[c + 1], gch[c + 1], d1);
        }
        const float dot = d0 + d1;
        s[k] = dot;
        const float mn = fmaxf(m, dot);
        const float rr = __expf(m - mn);     // 0 on first iter (m = -inf)
        const float pp = __expf(dot - mn);
        l = fmaf(l, rr, pp);
#pragma unroll
        for (int c = 0; c < C; c++) acc[c] = fmaf(acc[c], rr, pp * gch[c]);
        m = mn;
    }

    const float linv = 1.f / l;
    float o[C];
#pragma unroll
    for (int c = 0; c < C; c++) o[c] = acc[c] * linv;
    store_row20(out + (size_t)n * C, o);
#pragma unroll
    for (int k = 0; k < K; k++) wbuf[(size_t)n * K + k] = __expf(s[k] - m) * linv;
}

// ---------- kernel D: pass 2 aggregation with same weights, BN2 stats ----------

__global__ __launch_bounds__(BLK) void kD(const float* __restrict__ out,
                                          const int* __restrict__ index,
                                          const float* __restrict__ wbuf,
                                          float* __restrict__ out2,
                                          float* __restrict__ partials) {
    float sums[2 * C];
#pragma unroll
    for (int i = 0; i < 2 * C; i++) sums[i] = 0.f;

    for (int n = blockIdx.x * BLK + threadIdx.x; n < N_ROWS; n += GRID_RED * BLK) {
        float wv[K];
        int idx[K];
#pragma unroll
        for (int k = 0; k < K; k++) {
            wv[k] = wbuf[(size_t)n * K + k];
            idx[k] = index[(size_t)n * K + k];
        }
        float acc[C];
#pragma unroll
        for (int c = 0; c < C; c++) acc[c] = 0.f;
#pragma unroll
        for (int k = 0; k < K; k++) {
            float t[C];
            load_row20(out + (size_t)idx[k] * C, t);
#pragma unroll
            for (int c = 0; c < C; c++) acc[c] = fmaf(wv[k], t[c], acc[c]);
        }
        store_row20(out2 + (size_t)n * C, acc);
#pragma unroll
        for (int c = 0; c < C; c++) {
            sums[c] += acc[c];
            sums[C + c] = fmaf(acc[c], acc[c], sums[C + c]);
        }
    }
    block_reduce_partials(sums, partials);
}

// ---------- kernel F: z = [relu(bn2(out2)), feature] @ W3 + b3, BN3 stats (in-place) ----------

__global__ __launch_bounds__(BLK) void kF(const float* __restrict__ feat,
                                          const float* __restrict__ W3,
                                          const float* __restrict__ b3,
                                          const float* __restrict__ ss2,
                                          float* __restrict__ zio,
                                          float* __restrict__ partials) {
    float sums[2 * C];
#pragma unroll
    for (int i = 0; i < 2 * C; i++) sums[i] = 0.f;

    for (int n = blockIdx.x * BLK + threadIdx.x; n < N_ROWS; n += GRID_RED * BLK) {
        float h[2 * C];
        {
            float t[C];
            load_row20(zio + (size_t)n * C, t);
#pragma unroll
            for (int c = 0; c < C; c++) h[c] = fmaxf(0.f, fmaf(t[c], ss2[c], ss2[C + c]));
        }
        load_row20(feat + (size_t)n * C, h + C);

        float z[C];
#pragma unroll
        for (int c = 0; c < C; c++) z[c] = b3[c];
#pragma unroll
        for (int i = 0; i < 2 * C; i++) {
            float hi = h[i];
#pragma unroll
            for (int c = 0; c < C; c++) z[c] = fmaf(hi, W3[i * C + c], z[c]);
        }
        store_row20(zio + (size_t)n * C, z);
#pragma unroll
        for (int c = 0; c < C; c++) {
            sums[c] += z[c];
            sums[C + c] = fmaf(z[c], z[c], sums[C + c]);
        }
    }
    block_reduce_partials(sums, partials);
}

// ---------- kernel H: final bn3 + relu ----------

__global__ __launch_bounds__(BLK) void kH(const float* __restrict__ z,
                                          const float* __restrict__ ss3,
                                          float* __restrict__ outF) {
    for (int n = blockIdx.x * BLK + threadIdx.x; n < N_ROWS; n += GRID_RED * BLK) {
        float t[C];
        load_row20(z + (size_t)n * C, t);
        float o[C];
#pragma unroll
        for (int c = 0; c < C; c++) o[c] = fmaxf(0.f, fmaf(t[c], ss3[c], ss3[C + c]));
        store_row20(outF + (size_t)n * C, o);
    }
}

// ---------- launch ----------

extern "C" void kernel_launch(void* const* d_in, const int* in_sizes, int n_in,
                              void* d_out, int out_size, void* d_ws, size_t ws_size,
                              hipStream_t stream) {
    const float* feature = (const float*)d_in[0];
    const int* index = (const int*)d_in[1];
    const float* W1 = (const float*)d_in[2];
    const float* b1 = (const float*)d_in[3];
    const float* g1 = (const float*)d_in[4];
    const float* be1 = (const float*)d_in[5];
    const float* g2 = (const float*)d_in[6];
    const float* be2 = (const float*)d_in[7];
    const float* W3 = (const float*)d_in[8];
    const float* b3 = (const float*)d_in[9];
    const float* g3 = (const float*)d_in[10];
    const float* be3 = (const float*)d_in[11];
    float* outp = (float*)d_out;

    // ws layout: B0 (N*C, reused y1 -> out2 -> z), B1 (N*K weights),
    // partials (GRID_RED*40), ss1/ss2/ss3 (40 each). Total ~233 MB.
    float* B0 = (float*)d_ws;
    float* B1 = B0 + (size_t)N_ROWS * C;
    float* partials = B1 + (size_t)N_ROWS * K;
    float* ss1 = partials + (size_t)GRID_RED * (2 * C);
    float* ss2 = ss1 + 2 * C;
    float* ss3 = ss2 + 2 * C;

    const int gridC = (N_ROWS + BLK - 1) / BLK;

    kA<<<GRID_RED, BLK, 0, stream>>>(feature, W1, b1, B0, partials);
    kFin<<<1, 640, 0, stream>>>(partials, g1, be1, ss1);
    kC<<<gridC, BLK, 0, stream>>>(B0, index, ss1, outp, B1);
    kD<<<GRID_RED, BLK, 0, stream>>>(outp, index, B1, B0, partials);
    kFin<<<1, 640, 0, stream>>>(partials, g2, be2, ss2);
    kF<<<GRID_RED, BLK, 0, stream>>>(feature, W3, b3, ss2, B0, partials);
    kFin<<<1, 640, 0, stream>>>(partials, g3, be3, ss3);
    kH<<<GRID_RED, BLK, 0, stream>>>(B0, ss3, outp);
}